// Round 9
// baseline (453.122 us; speedup 1.0000x reference)
//
#include <hip/hip_runtime.h>
#include <math.h>

#define B_ROWS 4096
#define D_DIM  1024
static constexpr float TEMP = 0.2f;
static constexpr float FP8_SCALE = 16.0f;        // per-side scale before cast
static constexpr float INV_S2 = 1.0f / 256.0f;   // 1/SCALE^2: acc -> sim

typedef __attribute__((ext_vector_type(4)))  int   i32x4;
typedef __attribute__((ext_vector_type(8)))  int   i32x8;
typedef __attribute__((ext_vector_type(4)))  float f32x4;

// async global->LDS, 16 B/lane; LDS dest = wave-uniform base + lane*16
__device__ inline void gload_lds16(const unsigned char* g, unsigned char* l) {
    __builtin_amdgcn_global_load_lds(
        (const __attribute__((address_space(1))) unsigned int*)g,
        (__attribute__((address_space(3))) unsigned int*)l,
        16, 0, 0);
}

// read one 32-B fragment (two swizzled 16-B pieces) -> v8i32 MFMA operand
__device__ inline i32x8 read_frag(const unsigned char* p, int o0, int o1) {
    i32x4 lo = *(const i32x4*)(p + o0);
    i32x4 hi = *(const i32x4*)(p + o1);
    return __builtin_shufflevector(lo, hi, 0, 1, 2, 3, 4, 5, 6, 7);
}

// MX-scaled fp8 x fp8, K=128, unit E8M0 scales (0x7f = 2^0): fp8 GEMM at 2x
// rate with f32x4 accumulator (proven clean-alloc rounds 4/7/8; the 32x32x64
// f32x16-acc form spilled ~300 MB scratch in rounds 1-3).
#define MX_MFMA(A, Bv, C) __builtin_amdgcn_mfma_scale_f32_16x16x128_f8f6f4( \
    (A), (Bv), (C), 0, 0, 0, 0x7f7f7f7f, 0, 0x7f7f7f7f)

// pack 4 floats -> 4 fp8 e4m3fn bytes via HW converter (RNE, saturating)
__device__ inline unsigned int cvt4_fp8(float4 v) {
    int d = 0;
    d = __builtin_amdgcn_cvt_pk_fp8_f32(v.x, v.y, d, false);  // bytes 0,1
    d = __builtin_amdgcn_cvt_pk_fp8_f32(v.z, v.w, d, true);   // bytes 2,3
    return (unsigned int)d;
}

// ws layout: w[0]=pos acc, w[1]=neg acc, w[2]=finalize ticket (u32),
//            then Zi8 (4096x1024 fp8) at byte (w+16), Zj8 after.

// Wave-per-row normalize (fp32) + scale by 16 + cast to fp8 e4m3 (HW cvt).
// (round-8 version, measured fine: end-to-end gap shrank 3.7 us)
__global__ __launch_bounds__(256) void norm_cast_kernel(
        const float* __restrict__ emb_i, const float* __restrict__ emb_j,
        unsigned char* __restrict__ Zi8, unsigned char* __restrict__ Zj8,
        float* __restrict__ w) {
    const int tid = threadIdx.x;
    if (blockIdx.x == 0 && tid == 0) {
        w[0] = 0.0f; w[1] = 0.0f;
        ((unsigned int*)w)[2] = 0u;
    }
    const int wave = tid >> 6, lane = tid & 63;
    const int row = blockIdx.x * 4 + wave;          // 0..8191
    const float* src; unsigned char* dst; int r;
    if (row < B_ROWS) { src = emb_i; dst = Zi8; r = row; }
    else              { src = emb_j; dst = Zj8; r = row - B_ROWS; }

    const float4* p = (const float4*)(src + (size_t)r * D_DIM) + 4 * lane;
    float4 v0 = p[0], v1 = p[1], v2 = p[2], v3 = p[3];
    float s = v0.x*v0.x + v0.y*v0.y + v0.z*v0.z + v0.w*v0.w
            + v1.x*v1.x + v1.y*v1.y + v1.z*v1.z + v1.w*v1.w
            + v2.x*v2.x + v2.y*v2.y + v2.z*v2.z + v2.w*v2.w
            + v3.x*v3.x + v3.y*v3.y + v3.z*v3.z + v3.w*v3.w;
    #pragma unroll
    for (int m = 1; m < 64; m <<= 1) s += __shfl_xor(s, m, 64);
    const float inv = FP8_SCALE / fmaxf(sqrtf(s), 1e-12f);

    float4 a0 = {v0.x*inv, v0.y*inv, v0.z*inv, v0.w*inv};
    float4 a1 = {v1.x*inv, v1.y*inv, v1.z*inv, v1.w*inv};
    float4 a2 = {v2.x*inv, v2.y*inv, v2.z*inv, v2.w*inv};
    float4 a3 = {v3.x*inv, v3.y*inv, v3.z*inv, v3.w*inv};
    i32x4 o = { (int)cvt4_fp8(a0), (int)cvt4_fp8(a1),
                (int)cvt4_fp8(a2), (int)cvt4_fp8(a3) };
    ((i32x4*)(dst + (size_t)r * D_DIM))[lane] = o;   // 16 B/lane, unit stride
}

// 128x128 block tile, BK=128 bytes, 512 threads = 8 waves (2 row x 4 col):
// wave owns 64x32 = 4x2 MFMA tiles of 16x16x128 MX-fp8. Grid 1024 (T1).
//
// Round-9 structure: pipelining AND full wave residency simultaneously.
//  - full 64 KB LDS double-buffer -> 2 blocks/CU (128 KB), but 8 waves/block
//    keeps 16 waves/CU (the VGPR-92 ceiling round 7 already sat at).
//  - T3-minimum: STAGE(t+1 -> other buf) issued BEFORE ds_read+MFMA of t;
//    ONE barrier/iter; its vmcnt(0) drain lands after the compute phase
//    (round 4/7 exposed a full L2 round-trip per iter with zero overlap).
//  - __launch_bounds__(512,4) caps VGPR at 128: blocks round 6's 256-VGPR
//    hoisting. acc 32 + live frags 48 + addr ~ 100, no barrier-crossing frags.
//  - T5 setprio around the MFMA cluster (phase-diverse schedule -> pays).
//
// T1: bid%8 = XCD; each XCD owns a 16x8 rectangle of the 32x32 tile grid
// (3 MB working set < 4 MB L2; FETCH 18.5->12.4 MB verified round 7).
//
// LDS row = 128 B = 8 x 16-B pieces, XOR swizzle p = c ^ (r&7) (verified
// rounds 1-8). global_load_lds writes linearly; global source pre-swizzled.
__global__ __launch_bounds__(512, 4) void simloss_mfma_mxfp8_kernel(
        const unsigned char* __restrict__ Zi8,
        const unsigned char* __restrict__ Zj8,
        float* __restrict__ w, float* __restrict__ out) {
    __shared__ __align__(16) unsigned char lds[2 * 32768]; // [buf][A:16K|B:16K]
    __shared__ float rn[8], rp[8];

    const int tid  = threadIdx.x;
    const int lane = tid & 63;
    const int wave = tid >> 6;              // 0..7
    const int wy = wave >> 2, wx = wave & 3;   // wave tile: rows 64*wy, cols 32*wx

    // --- T1 XCD-rectangle swizzle (bijective on 32x32)
    const int bid = blockIdx.x;             // 0..1023
    const int xcd = bid & 7;
    const int loc = bid >> 3;               // 0..127
    const int by  = ((xcd >> 2) << 4) + (loc >> 3);   // 0..31
    const int bx  = ((xcd & 3) << 3) + (loc & 7);     // 0..31
    const int rowBase = by * 128;           // a (Zj rows)
    const int colBase = bx * 128;           // b (Zi rows)

    // --- staging: 32 chunks (8 rows x 128 B); wave stages 2 A + 2 B chunks
    //     (rows [16w, 16w+16) of each panel). lane l -> row l>>3, phys piece
    //     l&7, logical piece (l&7)^(l>>3) pre-swizzled on the global side.
    const int srow = lane >> 3;
    const int sc   = (lane & 7) ^ srow;
    const unsigned char* gA = Zj8 + (size_t)(rowBase + 16*wave + srow) * D_DIM + sc*16;
    const unsigned char* gB = Zi8 + (size_t)(colBase + 16*wave + srow) * D_DIM + sc*16;
    const int sAoff = wave * 2048;            // A region: buf + [0, 16K)
    const int sBoff = 16384 + wave * 2048;    // B region: buf + [16K, 32K)

#define STAGE(k0, bo) do {                                                     \
        _Pragma("unroll")                                                      \
        for (int n = 0; n < 2; ++n) {                                          \
            gload_lds16(gA + (size_t)(n*8) * D_DIM + (k0),                     \
                        lds + (bo) + sAoff + n*1024);                          \
            gload_lds16(gB + (size_t)(n*8) * D_DIM + (k0),                     \
                        lds + (bo) + sBoff + n*1024);                          \
        }                                                                      \
    } while (0)

    // --- fragment addressing (16x16x128): lane l holds row (l&15),
    //     k = (l>>4)*32 + 0..31 -> logical pieces {2g, 2g+1}, g = l>>4.
    //     physical = logical ^ (row&7); row&7 == lane&7 (row bases mult of 8).
    const int lr16 = lane & 15;
    const int g    = lane >> 4;
    const int o0 = ((((g << 1) + 0) ^ (lane & 7)) << 4);
    const int o1 = ((((g << 1) + 1) ^ (lane & 7)) << 4);
    const int fAoff = (wy * 64 + lr16) * 128;          // + i*16*128 (i=0..3)
    const int fBoff = 16384 + (wx * 32 + lr16) * 128;  // + j*16*128 (j=0..1)

    f32x4 acc[4][2];
    #pragma unroll
    for (int i = 0; i < 4; ++i)
        #pragma unroll
        for (int j = 0; j < 2; ++j)
            acc[i][j] = (f32x4){0.f, 0.f, 0.f, 0.f};

    STAGE(0, 0);
    __syncthreads();                        // prologue tile visible
    int cur = 0;
    for (int it = 0; it < 8; ++it) {
        if (it < 7) STAGE((it + 1) * 128, cur ^ 32768);  // fly under compute

        const unsigned char* fA = lds + cur + fAoff;
        const unsigned char* fB = lds + cur + fBoff;
        i32x8 a0 = read_frag(fA,        o0, o1);
        i32x8 a1 = read_frag(fA + 2048, o0, o1);
        i32x8 a2 = read_frag(fA + 4096, o0, o1);
        i32x8 a3 = read_frag(fA + 6144, o0, o1);
        i32x8 b0 = read_frag(fB,        o0, o1);
        i32x8 b1 = read_frag(fB + 2048, o0, o1);
        __builtin_amdgcn_s_setprio(1);
        acc[0][0] = MX_MFMA(a0, b0, acc[0][0]);
        acc[0][1] = MX_MFMA(a0, b1, acc[0][1]);
        acc[1][0] = MX_MFMA(a1, b0, acc[1][0]);
        acc[1][1] = MX_MFMA(a1, b1, acc[1][1]);
        acc[2][0] = MX_MFMA(a2, b0, acc[2][0]);
        acc[2][1] = MX_MFMA(a2, b1, acc[2][1]);
        acc[3][0] = MX_MFMA(a3, b0, acc[3][0]);
        acc[3][1] = MX_MFMA(a3, b1, acc[3][1]);
        __builtin_amdgcn_s_setprio(0);

        __syncthreads();    // drains vmcnt: next tile ready; readers done
        cur ^= 32768;
    }
#undef STAGE

    // --- fused epilogue; 16x16 C layout: col=lane&15, row=(lane>>4)*4+reg
    float neg = 0.f, pos = 0.f;
    const int bc = colBase + wx * 32 + lr16;
    #pragma unroll
    for (int i = 0; i < 4; ++i) {
        const int abase = rowBase + wy * 64 + i * 16 + g * 4;
        #pragma unroll
        for (int j = 0; j < 2; ++j) {
            const int b = bc + j * 16;
            #pragma unroll
            for (int r = 0; r < 4; ++r) {
                const float x = acc[i][j][r] * INV_S2 - TEMP;   // sim - T
                if (abase + r == b) pos += __logf(1.0f + __expf(-x));
                else                neg += __logf(1.0f + __expf(x));
            }
        }
    }
    #pragma unroll
    for (int o = 32; o > 0; o >>= 1) {
        neg += __shfl_down(neg, o, 64);
        pos += __shfl_down(pos, o, 64);
    }
    if (lane == 0) { rn[wave] = neg; rp[wave] = pos; }
    __syncthreads();
    if (tid == 0) {
        float n8 = 0.f, p8 = 0.f;
        #pragma unroll
        for (int k = 0; k < 8; ++k) { n8 += rn[k]; p8 += rp[k]; }
        atomicAdd(&w[1], n8);
        if (bx == by) atomicAdd(&w[0], p8);              // tile holding diagonal
        __threadfence();
        unsigned int done = atomicAdd(((unsigned int*)w) + 2, 1u);
        if (done == gridDim.x - 1) {                     // last block finalizes
            const float psum = atomicAdd(&w[0], 0.0f);
            const float nsum = atomicAdd(&w[1], 0.0f);
            out[0] = 0.5f * (psum / (float)B_ROWS)
                   + 0.5f * (nsum / ((float)B_ROWS * (float)(B_ROWS - 1)));
        }
    }
}

extern "C" void kernel_launch(void* const* d_in, const int* in_sizes, int n_in,
                              void* d_out, int out_size, void* d_ws, size_t ws_size,
                              hipStream_t stream) {
    const float* emb_i = (const float*)d_in[0];
    const float* emb_j = (const float*)d_in[1];
    float* w = (float*)d_ws;
    unsigned char* Zi8 = (unsigned char*)(w + 16);
    unsigned char* Zj8 = Zi8 + (size_t)B_ROWS * D_DIM;
    float* out = (float*)d_out;

    norm_cast_kernel<<<2 * B_ROWS / 4, 256, 0, stream>>>(emb_i, emb_j, Zi8, Zj8, w);
    simloss_mfma_mxfp8_kernel<<<1024, 512, 0, stream>>>(Zi8, Zj8, w, out);
}